// Round 2
// baseline (1989.648 us; speedup 1.0000x reference)
//
#include <hip/hip_runtime.h>
#include <hip/hip_cooperative_groups.h>
#include <math.h>

namespace cg = cooperative_groups;

#define N_TOTAL    68096
#define NUM_INPUT  2048
#define NUM_OUTPUT 512
#define OUT_START  67584   // NUM_INPUT + NUM_HIDDEN
#define FAN_OUT    256
#define THRESH     0.3f
#define T_MAX      50
#define GRID_BLKS  512
#define BLK        256

// Single persistent cooperative kernel. Thread gtid owns neuron gtid
// (gsz = 131072 >= N_TOTAL): pot / last_update / fired live in REGISTERS
// for the whole simulation. Only acc[], frontier[2][], cnt[] are in memory.
// Touched-detection via acc != 0 (exact: zero-sum touch cannot change
// spiking — resting non-fired pot < THRESH and decay is multiplicative/lazy).
__global__ __launch_bounds__(BLK, 2) void snn_coop(
    const unsigned int* __restrict__ in0,
    const float* __restrict__ weights,
    const int*  __restrict__ targets,
    float* __restrict__ out_f,     // [0..511]=times(float), [512..1023]=pot
    float* __restrict__ acc,
    int*   __restrict__ fr0,
    int*   __restrict__ fr1,
    int*   __restrict__ cnt)       // cnt[0], cnt[1], cnt[2]=mode
{
    cg::grid_group grid = cg::this_grid();
    const int gtid = blockIdx.x * BLK + threadIdx.x;
    const int gsz  = GRID_BLKS * BLK;
    const int lane = threadIdx.x & 63;

    // per-block decay table: decay_base ** dt, dt in [0,50]
    __shared__ float s_decay[T_MAX + 1];
    if (threadIdx.x <= T_MAX) {
        float base = expf(-0.05f);
        s_decay[threadIdx.x] = (float)pow((double)base, (double)threadIdx.x);
    }

    // ---- input dtype detection (bool as int32 / float32 / packed uint8) ----
    if (blockIdx.x == 0) {
        __shared__ int sF, sG;
        if (threadIdx.x == 0) { sF = 0; sG = 0; }
        __syncthreads();
        for (int k = threadIdx.x; k < 512; k += BLK) {   // 2048 bytes, safe
            unsigned int v = in0[k];
            if (v == 0x3F800000u) atomicAdd(&sF, 1);
            else if (v > 1u)      sG = 1;                // benign race
        }
        __syncthreads();
        if (threadIdx.x == 0) cnt[2] = (sF >= 8) ? 1 : (sG ? 2 : 0);
    }
    __syncthreads();            // s_decay ready
    grid.sync();

    const int mode = cnt[2];
    const int n = gtid;         // neuron id owned by this thread (if < N_TOTAL)
    float pot     = 0.0f;
    int   last_up = 0;
    bool  fired   = false;

    if (n < N_TOTAL)    acc[n]   = 0.0f;
    if (n < NUM_OUTPUT) out_f[n] = -1.0f;

    // build frontier0 from input spikes (wave-aggregated append)
    {
        bool want = false;
        if (n < NUM_INPUT) {
            bool s;
            if (mode == 0)      s = ((const int*)in0)[n] != 0;
            else if (mode == 1) s = ((const float*)in0)[n] != 0.0f;
            else                s = ((const unsigned char*)in0)[n] != 0;
            fired = s;
            want  = s;
        }
        unsigned long long m = __ballot(want);
        if (m) {
            int leader = __ffsll((long long)m) - 1;
            int base = 0;
            if (lane == leader) base = atomicAdd(&cnt[0], __popcll(m));
            base = __shfl(base, leader, 64);
            if (want) {
                int off = __popcll(m & ((1ull << (unsigned)lane) - 1ull));
                fr0[base + off] = n;
            }
        }
    }
    grid.sync();

    for (int t = 0; t < T_MAX; ++t) {
        const int fc = t & 1;
        const int fcnt = __hip_atomic_load(&cnt[fc], __ATOMIC_RELAXED,
                                           __HIP_MEMORY_SCOPE_AGENT);
        if (fcnt == 0) break;   // frontier empty -> nothing can ever change

        // ---- phase A: scatter this step's spikes ----
        if (gtid == 0) cnt[1 - fc] = 0;
        const int* fr = (fc == 0) ? fr0 : fr1;
        const int nq = fcnt * (FAN_OUT / 4);   // quad-edges
        for (int q = gtid; q < nq; q += gsz) {
            int s  = fr[q >> 6];               // wave-uniform source
            int j4 = (q & 63) << 2;
            const int base = s * FAN_OUT + j4;
            int4   tg = *(const int4*)  (targets + base);
            float4 wv = *(const float4*)(weights + base);
            float  st = (s < NUM_INPUT) ? 2.0f : 1.0f;
            atomicAdd(&acc[tg.x], st * wv.x);
            atomicAdd(&acc[tg.y], st * wv.y);
            atomicAdd(&acc[tg.z], st * wv.z);
            atomicAdd(&acc[tg.w], st * wv.w);
        }
        grid.sync();

        // ---- phase B: integrate touched neurons (owner thread, registers) ----
        bool w2 = false;
        if (n < N_TOTAL) {
            float a = acc[n];
            if (a != 0.0f) {
                acc[n] = 0.0f;
                float p = pot * s_decay[t - last_up] + a;
                last_up = t;
                if (!fired && p >= THRESH) {
                    fired = true;
                    if (n < OUT_START) { p = 0.0f; w2 = true; }  // deliver t+1
                    else out_f[n - OUT_START] = (float)t;        // first fire
                }
                pot = p;
            }
        }
        {
            unsigned long long m = __ballot(w2);
            if (m) {
                int leader = __ffsll((long long)m) - 1;
                int base = 0;
                if (lane == leader) base = atomicAdd(&cnt[1 - fc], __popcll(m));
                base = __shfl(base, leader, 64);
                if (w2) {
                    int off = __popcll(m & ((1ull << (unsigned)lane) - 1ull));
                    ((fc == 0) ? fr1 : fr0)[base + off] = n;
                }
            }
        }
        grid.sync();
    }

    // ---- final decay to end of window for output potentials ----
    if (n >= OUT_START && n < N_TOTAL) {
        out_f[NUM_OUTPUT + (n - OUT_START)] = pot * s_decay[T_MAX - last_up];
    }
}

extern "C" void kernel_launch(void* const* d_in, const int* in_sizes, int n_in,
                              void* d_out, int out_size, void* d_ws, size_t ws_size,
                              hipStream_t stream) {
    const void*  in_spikes = d_in[0];
    const float* weights   = (const float*)d_in[1];
    const int*   targets   = (const int*)d_in[2];
    float*       out_f     = (float*)d_out;

    char* w = (char*)d_ws;
    int*   cnt = (int*)w;                    // [0],[1]=frontier counts, [2]=mode
    float* acc = (float*)(w + 256);
    int*   fr0 = (int*)(acc + N_TOTAL);
    int*   fr1 = fr0 + N_TOTAL;

    hipMemsetAsync(cnt, 0, 16, stream);

    void* args[] = {
        (void*)&in_spikes, (void*)&weights, (void*)&targets,
        (void*)&out_f, (void*)&acc, (void*)&fr0, (void*)&fr1, (void*)&cnt
    };
    hipLaunchCooperativeKernel((const void*)snn_coop,
                               dim3(GRID_BLKS), dim3(BLK),
                               args, 0, stream);
}

// Round 3
// 788.535 us; speedup vs baseline: 2.5232x; 2.5232x over previous
//
#include <hip/hip_runtime.h>
#include <math.h>

#define N_TOTAL    68096
#define NUM_INPUT  2048
#define NUM_OUTPUT 512
#define OUT_START  67584   // NUM_INPUT + NUM_HIDDEN
#define N_TGT      66048   // N_TOTAL - NUM_INPUT (all targets >= NUM_INPUT)
#define FAN_OUT    256
#define THRESH     0.3f
#define T_MAX      50
#define T_BIG      12      // steps [0, T_BIG) via multi-launch; rest in tail_k
#define BM_WORDS   2064    // ceil(66048 / 32)
#define LIST_CAP   12288

// ---- input-bool dtype detection (int32 / float32 / packed uint8) ----------
__global__ void detect_mode_k(const unsigned int* in0, int* mode) {
    __shared__ int cntF, anyG;
    if (threadIdx.x == 0) { cntF = 0; anyG = 0; }
    __syncthreads();
    unsigned int v = in0[threadIdx.x];          // 512 threads, 2048B: safe
    if (v == 0x3F800000u) atomicAdd(&cntF, 1);
    else if (v > 1u)      atomicOr(&anyG, 1);
    __syncthreads();
    if (threadIdx.x == 0) *mode = (cntF >= 8) ? 1 : (anyG ? 2 : 0);
}

__global__ __launch_bounds__(256) void init_k(
    const void* in0, const int* mode_p,
    float* pot, float* acc, int* last_up, unsigned char* fired,
    int* frontier0, int* cnt, float* out_f, float* decay_tab)
{
    int i = blockIdx.x * 256 + threadIdx.x;     // grid 266 -> covers N_TOTAL
    int lane = threadIdx.x & 63;
    int mode = *mode_p;
    if (i <= T_MAX) {
        // EXACT match to validated path: f64 pow of f32 exp(-0.05)
        float base = expf(-0.05f);
        decay_tab[i] = (float)pow((double)base, (double)i);
    }
    if (i < NUM_OUTPUT) out_f[i] = -1.0f;       // out_times init
    bool want = false;
    if (i < N_TOTAL) {
        pot[i] = 0.0f;
        acc[i] = 0.0f;
        last_up[i] = 0;
        bool s = false;
        if (i < NUM_INPUT) {
            if (mode == 0)      s = ((const int*)in0)[i] != 0;
            else if (mode == 1) s = ((const float*)in0)[i] != 0.0f;
            else                s = ((const unsigned char*)in0)[i] != 0;
        }
        fired[i] = s ? 1 : 0;
        want = s;
    }
    unsigned long long m = __ballot(want);
    if (m) {
        int leader = __ffsll((long long)m) - 1;
        int base = 0;
        if (lane == leader) base = atomicAdd(&cnt[0], __popcll(m));
        base = __shfl(base, leader, 64);
        if (want) {
            int off = __popcll(m & ((1ull << (unsigned)lane) - 1ull));
            frontier0[base + off] = i;
        }
    }
}

// big-step scatter: deliver frontier spikes into acc
__global__ __launch_bounds__(256) void scatter_k(
    const int* __restrict__ frontier, const int* __restrict__ cnt_cur,
    int* cnt_next,
    const int* __restrict__ targets, const float* __restrict__ weights,
    float* __restrict__ acc)
{
    if (blockIdx.x == 0 && threadIdx.x == 0) *cnt_next = 0;
    const int nq = (*cnt_cur) * (FAN_OUT / 4);
    const int stride = gridDim.x * 256;
    for (int q = blockIdx.x * 256 + threadIdx.x; q < nq; q += stride) {
        int s  = frontier[q >> 6];              // wave-uniform source
        int j4 = (q & 63) << 2;
        const int base = s * FAN_OUT + j4;
        int4   tg = *(const int4*)  (targets + base);
        float4 wv = *(const float4*)(weights + base);
        float  st = (s < NUM_INPUT) ? 2.0f : 1.0f;
        atomicAdd(&acc[tg.x], st * wv.x);
        atomicAdd(&acc[tg.y], st * wv.y);
        atomicAdd(&acc[tg.z], st * wv.z);
        atomicAdd(&acc[tg.w], st * wv.w);
    }
}

// big-step update: sweep all possible targets [NUM_INPUT, N_TOTAL)
__global__ __launch_bounds__(256) void update_k(
    float* __restrict__ pot, float* __restrict__ acc,
    int* __restrict__ last_up, unsigned char* __restrict__ fired,
    int* __restrict__ frontier_next, int* __restrict__ cnt_next,
    float* __restrict__ out_f, const float* __restrict__ decay_tab, int t)
{
    const int n = NUM_INPUT + blockIdx.x * 256 + threadIdx.x;  // grid 258 exact
    const int lane = threadIdx.x & 63;
    bool w2 = false;
    float a = acc[n];
    if (a != 0.0f) {
        acc[n] = 0.0f;
        float p = pot[n] * decay_tab[t - last_up[n]] + a;
        last_up[n] = t;
        if (!fired[n] && p >= THRESH) {
            fired[n] = 1;
            if (n < OUT_START) { p = 0.0f; w2 = true; }
            else out_f[n - OUT_START] = (float)t;
        }
        pot[n] = p;
    }
    unsigned long long m = __ballot(w2);
    if (m) {
        int leader = __ffsll((long long)m) - 1;
        int base = 0;
        if (lane == leader) base = atomicAdd(cnt_next, __popcll(m));
        base = __shfl(base, leader, 64);
        if (w2) {
            int off = __popcll(m & ((1ull << (unsigned)lane) - 1ull));
            frontier_next[base + off] = n;
        }
    }
}

// tail: one workgroup runs steps [T_BIG, 50) with __syncthreads barriers,
// LDS-bitmap touched-list, early exit when frontier empties; writes out_pot.
__global__ __launch_bounds__(1024) void tail_k(
    float* __restrict__ pot, float* __restrict__ acc,
    int* __restrict__ last_up, unsigned char* __restrict__ fired,
    int* __restrict__ fr0, int* __restrict__ fr1, int* __restrict__ cnt,
    const int* __restrict__ targets, const float* __restrict__ weights,
    float* __restrict__ out_f, const float* __restrict__ decay_tab)
{
    __shared__ unsigned bm[BM_WORDS];
    __shared__ int      lst[LIST_CAP];
    __shared__ int      lcnt, ovf;
    __shared__ float    sdecay[T_MAX + 1];
    const int tid = threadIdx.x;
    if (tid <= T_MAX) sdecay[tid] = decay_tab[tid];

    for (int t = T_BIG; t < T_MAX; ++t) {
        const int cur = t & 1, nxt = cur ^ 1;
        for (int k = tid; k < BM_WORDS; k += 1024) bm[k] = 0u;
        if (tid == 0) { lcnt = 0; ovf = 0; cnt[nxt] = 0; }
        __syncthreads();
        const int fcnt = cnt[cur];
        if (fcnt == 0) break;                    // frontier dead: done forever
        const int* fr  = (cur == 0) ? fr0 : fr1;
        int*       frn = (cur == 0) ? fr1 : fr0;

        // ---- scatter + touched-list ----
        const int nq = fcnt * (FAN_OUT / 4);
        for (int q = tid; q < nq; q += 1024) {
            int s  = fr[q >> 6];
            int j4 = (q & 63) << 2;
            const int base = s * FAN_OUT + j4;
            int4   tg = *(const int4*)  (targets + base);
            float4 wv = *(const float4*)(weights + base);
            float  st = (s < NUM_INPUT) ? 2.0f : 1.0f;
            #define EDGE(TG, WV) do {                                         \
                atomicAdd(&acc[TG], st * (WV));                               \
                int b = (TG) - NUM_INPUT;                                     \
                unsigned bit = 1u << (b & 31);                                \
                unsigned old = atomicOr(&bm[b >> 5], bit);                    \
                if (!(old & bit)) {                                           \
                    int p_ = atomicAdd(&lcnt, 1);                             \
                    if (p_ < LIST_CAP) lst[p_] = (TG); else ovf = 1;          \
                } } while (0)
            EDGE(tg.x, wv.x); EDGE(tg.y, wv.y);
            EDGE(tg.z, wv.z); EDGE(tg.w, wv.w);
            #undef EDGE
        }
        __syncthreads();

        // ---- update touched ----
        const int M = lcnt;
        const bool full = (ovf != 0);
        const int lo  = full ? (NUM_INPUT + tid) : tid;
        const int hi  = full ? N_TOTAL : M;
        for (int k = lo; k < hi; k += 1024) {
            const int n = full ? k : lst[k];
            float a = __hip_atomic_load(&acc[n], __ATOMIC_RELAXED,
                                        __HIP_MEMORY_SCOPE_AGENT);
            if (a != 0.0f) {
                __hip_atomic_store(&acc[n], 0.0f, __ATOMIC_RELAXED,
                                   __HIP_MEMORY_SCOPE_AGENT);
                float p = pot[n] * sdecay[t - last_up[n]] + a;
                last_up[n] = t;
                if (!fired[n] && p >= THRESH) {
                    fired[n] = 1;
                    if (n < OUT_START) {
                        p = 0.0f;
                        int pos = atomicAdd(&cnt[nxt], 1);
                        frn[pos] = n;
                    } else out_f[n - OUT_START] = (float)t;
                }
                pot[n] = p;
            }
        }
        __syncthreads();
    }

    __syncthreads();
    for (int i = tid; i < NUM_OUTPUT; i += 1024) {
        int n = OUT_START + i;
        out_f[NUM_OUTPUT + i] = pot[n] * sdecay[T_MAX - last_up[n]];
    }
}

extern "C" void kernel_launch(void* const* d_in, const int* in_sizes, int n_in,
                              void* d_out, int out_size, void* d_ws, size_t ws_size,
                              hipStream_t stream) {
    const void*  in_spikes = d_in[0];
    const float* weights   = (const float*)d_in[1];
    const int*   targets   = (const int*)d_in[2];
    float*       out_f     = (float*)d_out;

    char* w = (char*)d_ws;
    int*   cnt       = (int*)w;                  // [0],[1] frontier counts
    int*   mode      = (int*)(w + 16);
    float* decay_tab = (float*)(w + 256);        // 51 floats
    float* pot       = (float*)(w + 512);
    float* acc       = pot + N_TOTAL;
    int*   last_up   = (int*)(acc + N_TOTAL);
    int*   fr0       = last_up + N_TOTAL;
    int*   fr1       = fr0 + N_TOTAL;
    unsigned char* fired = (unsigned char*)(fr1 + N_TOTAL);

    hipMemsetAsync(cnt, 0, 16, stream);
    detect_mode_k<<<1, 512, 0, stream>>>((const unsigned int*)in_spikes, mode);
    init_k<<<266, 256, 0, stream>>>(in_spikes, mode, pot, acc, last_up, fired,
                                    fr0, cnt, out_f, decay_tab);

    int* fr[2] = {fr0, fr1};
    for (int t = 0; t < T_BIG; ++t) {
        const int cur = t & 1, nxt = cur ^ 1;
        scatter_k<<<512, 256, 0, stream>>>(fr[cur], &cnt[cur], &cnt[nxt],
                                           targets, weights, acc);
        update_k<<<258, 256, 0, stream>>>(pot, acc, last_up, fired,
                                          fr[nxt], &cnt[nxt], out_f,
                                          decay_tab, t);
    }
    tail_k<<<1, 1024, 0, stream>>>(pot, acc, last_up, fired, fr0, fr1, cnt,
                                   targets, weights, out_f, decay_tab);
}

// Round 4
// 308.894 us; speedup vs baseline: 6.4412x; 2.5528x over previous
//
#include <hip/hip_runtime.h>
#include <math.h>

#define N_TOTAL    68096
#define NUM_INPUT  2048
#define NUM_OUTPUT 512
#define OUT_START  67584   // NUM_INPUT + NUM_HIDDEN
#define FAN_OUT    256
#define THRESH     0.3f
#define T_MAX      50
#define T_BIG      12      // steps [0, T_BIG) multi-launch; rest in tail_k
#define BM_WORDS   2064    // ceil(66048 / 32)
#define LIST_CAP   12288

#define HALF_SZ    33024   // (N_TOTAL - NUM_INPUT) / 2  targets per half
#define N_CHUNK    128     // frontier chunks in dense mode
#define DENSE_THR  1500    // frontier size above which dense path engages
#define DENSE_T_LO 1
#define DENSE_T_HI 3

// ---------------------------------------------------------------------------
// init: decay table, state arrays, frontier0 from input spikes.
// Input-bool dtype (int32/float32/uint8) detected per-block (2 KB scan).
// ---------------------------------------------------------------------------
__global__ __launch_bounds__(256) void init_k(
    const unsigned int* __restrict__ in0,
    float* pot, float* acc, int* last_up, unsigned char* fired,
    int* frontier0, int* cnt, float* out_f, float* decay_tab)
{
    __shared__ int sF, sG;
    const int tid = threadIdx.x;
    if (tid == 0) { sF = 0; sG = 0; }
    __syncthreads();
    for (int k = tid; k < 512; k += 256) {       // 2048 bytes: safe all modes
        unsigned int v = in0[k];
        if (v == 0x3F800000u) atomicAdd(&sF, 1);
        else if (v > 1u)      sG = 1;            // benign race
    }
    __syncthreads();
    const int mode = (sF >= 8) ? 1 : (sG ? 2 : 0);

    const int i = blockIdx.x * 256 + tid;
    const int lane = tid & 63;
    if (i <= T_MAX) {
        float base = expf(-0.05f);               // exact validated path
        decay_tab[i] = (float)pow((double)base, (double)i);
    }
    if (i < NUM_OUTPUT) out_f[i] = -1.0f;
    bool want = false;
    if (i < N_TOTAL) {
        pot[i] = 0.0f;
        acc[i] = 0.0f;
        last_up[i] = 0;
        bool s = false;
        if (i < NUM_INPUT) {
            if (mode == 0)      s = ((const int*)in0)[i] != 0;
            else if (mode == 1) s = ((const float*)in0)[i] != 0.0f;
            else                s = ((const unsigned char*)in0)[i] != 0;
        }
        fired[i] = s ? 1 : 0;
        want = s;
    }
    unsigned long long m = __ballot(want);
    if (m) {
        int leader = __ffsll((long long)m) - 1;
        int base = 0;
        if (lane == leader) base = atomicAdd(&cnt[0], __popcll(m));
        base = __shfl(base, leader, 64);
        if (want) {
            int off = __popcll(m & ((1ull << (unsigned)lane) - 1ull));
            frontier0[base + off] = i;
        }
    }
}

// ---------------------------------------------------------------------------
// sparse scatter (runs when fcnt < gate): device atomics into acc
// ---------------------------------------------------------------------------
__global__ __launch_bounds__(256) void scatter_k(
    const int* __restrict__ frontier, const int* __restrict__ cnt_cur,
    int* cnt_next,
    const int* __restrict__ targets, const float* __restrict__ weights,
    float* __restrict__ acc, int gate)
{
    if (blockIdx.x == 0 && threadIdx.x == 0) *cnt_next = 0;
    const int fcnt = *cnt_cur;
    if (fcnt >= gate) return;
    const int nq = fcnt * (FAN_OUT / 4);
    const int stride = gridDim.x * 256;
    for (int q = blockIdx.x * 256 + threadIdx.x; q < nq; q += stride) {
        int s  = frontier[q >> 6];               // wave-uniform source
        int j4 = (q & 63) << 2;
        const int base = s * FAN_OUT + j4;
        int4   tg = *(const int4*)  (targets + base);
        float4 wv = *(const float4*)(weights + base);
        float  st = (s < NUM_INPUT) ? 2.0f : 1.0f;
        atomicAdd(&acc[tg.x], st * wv.x);
        atomicAdd(&acc[tg.y], st * wv.y);
        atomicAdd(&acc[tg.z], st * wv.z);
        atomicAdd(&acc[tg.w], st * wv.w);
    }
}

// ---------------------------------------------------------------------------
// sparse update (runs when fcnt < gate): sweep all targets, consume acc
// ---------------------------------------------------------------------------
__global__ __launch_bounds__(256) void update_k(
    float* __restrict__ pot, float* __restrict__ acc,
    int* __restrict__ last_up, unsigned char* __restrict__ fired,
    int* __restrict__ frontier_next, int* __restrict__ cnt_next,
    float* __restrict__ out_f, const float* __restrict__ decay_tab, int t,
    const int* __restrict__ cnt_cur, int gate)
{
    if (*cnt_cur >= gate) return;
    const int n = NUM_INPUT + blockIdx.x * 256 + threadIdx.x;  // grid 258 exact
    const int lane = threadIdx.x & 63;
    bool w2 = false;
    float a = acc[n];
    if (a != 0.0f) {
        acc[n] = 0.0f;
        float p = pot[n] * decay_tab[t - last_up[n]] + a;
        last_up[n] = t;
        if (!fired[n] && p >= THRESH) {
            fired[n] = 1;
            if (n < OUT_START) { p = 0.0f; w2 = true; }
            else out_f[n - OUT_START] = (float)t;
        }
        pot[n] = p;
    }
    unsigned long long m = __ballot(w2);
    if (m) {
        int leader = __ffsll((long long)m) - 1;
        int base = 0;
        if (lane == leader) base = atomicAdd(cnt_next, __popcll(m));
        base = __shfl(base, leader, 64);
        if (w2) {
            int off = __popcll(m & ((1ull << (unsigned)lane) - 1ull));
            frontier_next[base + off] = n;
        }
    }
}

// ---------------------------------------------------------------------------
// dense scatter (fcnt >= DENSE_THR): block (chunk c, half h) accumulates its
// frontier chunk's in-range edges in a 132 KB LDS array (LDS atomics only),
// then writes the private partial to rep[c][h][.] with plain stores.
// Kernel boundary provides cross-XCD coherence for the reduce.
// ---------------------------------------------------------------------------
__global__ __launch_bounds__(1024) void dense_scatter_k(
    const int* __restrict__ fr, const int* __restrict__ cnt_cur,
    const int* __restrict__ targets, const float* __restrict__ weights,
    float* __restrict__ rep)
{
    const int fcnt = *cnt_cur;
    if (fcnt < DENSE_THR) return;
    __shared__ float lacc[HALF_SZ];              // 132 KB
    const int h    = blockIdx.x & 1;
    const int c    = blockIdx.x >> 1;
    const int base = NUM_INPUT + h * HALF_SZ;
    const int tid  = threadIdx.x;
    for (int k = tid; k < HALF_SZ / 4; k += 1024)
        ((float4*)lacc)[k] = make_float4(0.f, 0.f, 0.f, 0.f);
    __syncthreads();
    const int lo = (int)(((long long)fcnt * c)       / N_CHUNK);
    const int hi = (int)(((long long)fcnt * (c + 1)) / N_CHUNK);
    const int nq = (hi - lo) << 6;
    for (int q = tid; q < nq; q += 1024) {
        const int s  = fr[lo + (q >> 6)];        // wave-uniform source
        const int j4 = (q & 63) << 2;
        const int eb = s * FAN_OUT + j4;
        int4   tg = *(const int4*)  (targets + eb);
        float4 wv = *(const float4*)(weights + eb);
        float  st = (s < NUM_INPUT) ? 2.0f : 1.0f;
        int x;
        x = tg.x - base; if ((unsigned)x < HALF_SZ) atomicAdd(&lacc[x], st * wv.x);
        x = tg.y - base; if ((unsigned)x < HALF_SZ) atomicAdd(&lacc[x], st * wv.y);
        x = tg.z - base; if ((unsigned)x < HALF_SZ) atomicAdd(&lacc[x], st * wv.z);
        x = tg.w - base; if ((unsigned)x < HALF_SZ) atomicAdd(&lacc[x], st * wv.w);
    }
    __syncthreads();
    float4* out = (float4*)(rep + (size_t)((c << 1) + h) * HALF_SZ);
    for (int k = tid; k < HALF_SZ / 4; k += 1024) out[k] = ((float4*)lacc)[k];
}

// ---------------------------------------------------------------------------
// dense update: per-target reduce of 128 partials, then identical update.
// ---------------------------------------------------------------------------
__global__ __launch_bounds__(1024) void dense_update_k(
    const float* __restrict__ rep, const int* __restrict__ cnt_cur,
    float* __restrict__ pot, int* __restrict__ last_up,
    unsigned char* __restrict__ fired,
    int* __restrict__ frontier_next, int* __restrict__ cnt_next,
    float* __restrict__ out_f, const float* __restrict__ decay_tab, int t)
{
    const int fcnt = *cnt_cur;
    if (fcnt < DENSE_THR) return;
    const int g = blockIdx.x * 1024 + threadIdx.x;   // 0 .. 66559
    const int lane = threadIdx.x & 63;
    bool w2 = false;
    const int n = NUM_INPUT + g;
    if (g < 2 * HALF_SZ) {
        const int h   = (g < HALF_SZ) ? 1 : 2;       // trick: h-1 below
        const int hh  = h - 1 ? 1 : 0;
        const int idx = g - hh * HALF_SZ;
        const float* p0 = rep + (size_t)hh * HALF_SZ + idx;
        float a0 = 0.f, a1 = 0.f, a2 = 0.f, a3 = 0.f;
        #pragma unroll 4
        for (int c = 0; c < N_CHUNK; c += 4) {
            a0 += p0[(size_t)((c + 0) << 1) * HALF_SZ];
            a1 += p0[(size_t)((c + 1) << 1) * HALF_SZ];
            a2 += p0[(size_t)((c + 2) << 1) * HALF_SZ];
            a3 += p0[(size_t)((c + 3) << 1) * HALF_SZ];
        }
        float a = (a0 + a1) + (a2 + a3);
        if (a != 0.0f) {
            float p = pot[n] * decay_tab[t - last_up[n]] + a;
            last_up[n] = t;
            if (!fired[n] && p >= THRESH) {
                fired[n] = 1;
                if (n < OUT_START) { p = 0.0f; w2 = true; }
                else out_f[n - OUT_START] = (float)t;
            }
            pot[n] = p;
        }
    }
    unsigned long long m = __ballot(w2);
    if (m) {
        int leader = __ffsll((long long)m) - 1;
        int base = 0;
        if (lane == leader) base = atomicAdd(cnt_next, __popcll(m));
        base = __shfl(base, leader, 64);
        if (w2) {
            int off = __popcll(m & ((1ull << (unsigned)lane) - 1ull));
            frontier_next[base + off] = n;
        }
    }
}

// ---------------------------------------------------------------------------
// tail: one workgroup runs steps [T_BIG, 50), __syncthreads barriers,
// LDS-bitmap touched-list, early exit; writes final out_pot.
// ---------------------------------------------------------------------------
__global__ __launch_bounds__(1024) void tail_k(
    float* __restrict__ pot, float* __restrict__ acc,
    int* __restrict__ last_up, unsigned char* __restrict__ fired,
    int* __restrict__ fr0, int* __restrict__ fr1, int* __restrict__ cnt,
    const int* __restrict__ targets, const float* __restrict__ weights,
    float* __restrict__ out_f, const float* __restrict__ decay_tab)
{
    __shared__ unsigned bm[BM_WORDS];
    __shared__ int      lst[LIST_CAP];
    __shared__ int      lcnt, ovf;
    __shared__ float    sdecay[T_MAX + 1];
    const int tid = threadIdx.x;
    if (tid <= T_MAX) sdecay[tid] = decay_tab[tid];

    for (int t = T_BIG; t < T_MAX; ++t) {
        const int cur = t & 1, nxt = cur ^ 1;
        for (int k = tid; k < BM_WORDS; k += 1024) bm[k] = 0u;
        if (tid == 0) { lcnt = 0; ovf = 0; cnt[nxt] = 0; }
        __syncthreads();
        const int fcnt = cnt[cur];
        if (fcnt == 0) break;
        const int* fr  = (cur == 0) ? fr0 : fr1;
        int*       frn = (cur == 0) ? fr1 : fr0;

        const int nq = fcnt * (FAN_OUT / 4);
        for (int q = tid; q < nq; q += 1024) {
            int s  = fr[q >> 6];
            int j4 = (q & 63) << 2;
            const int base = s * FAN_OUT + j4;
            int4   tg = *(const int4*)  (targets + base);
            float4 wv = *(const float4*)(weights + base);
            float  st = (s < NUM_INPUT) ? 2.0f : 1.0f;
            #define EDGE(TG, WV) do {                                         \
                atomicAdd(&acc[TG], st * (WV));                               \
                int b = (TG) - NUM_INPUT;                                     \
                unsigned bit = 1u << (b & 31);                                \
                unsigned old = atomicOr(&bm[b >> 5], bit);                    \
                if (!(old & bit)) {                                           \
                    int p_ = atomicAdd(&lcnt, 1);                             \
                    if (p_ < LIST_CAP) lst[p_] = (TG); else ovf = 1;          \
                } } while (0)
            EDGE(tg.x, wv.x); EDGE(tg.y, wv.y);
            EDGE(tg.z, wv.z); EDGE(tg.w, wv.w);
            #undef EDGE
        }
        __syncthreads();

        const int M = lcnt;
        const bool full = (ovf != 0);
        const int lo = full ? (NUM_INPUT + tid) : tid;
        const int hi = full ? N_TOTAL : M;
        for (int k = lo; k < hi; k += 1024) {
            const int n = full ? k : lst[k];
            float a = __hip_atomic_load(&acc[n], __ATOMIC_RELAXED,
                                        __HIP_MEMORY_SCOPE_AGENT);
            if (a != 0.0f) {
                __hip_atomic_store(&acc[n], 0.0f, __ATOMIC_RELAXED,
                                   __HIP_MEMORY_SCOPE_AGENT);
                float p = pot[n] * sdecay[t - last_up[n]] + a;
                last_up[n] = t;
                if (!fired[n] && p >= THRESH) {
                    fired[n] = 1;
                    if (n < OUT_START) {
                        p = 0.0f;
                        int pos = atomicAdd(&cnt[nxt], 1);
                        frn[pos] = n;
                    } else out_f[n - OUT_START] = (float)t;
                }
                pot[n] = p;
            }
        }
        __syncthreads();
    }

    __syncthreads();
    for (int i = tid; i < NUM_OUTPUT; i += 1024) {
        int n = OUT_START + i;
        out_f[NUM_OUTPUT + i] = pot[n] * sdecay[T_MAX - last_up[n]];
    }
}

extern "C" void kernel_launch(void* const* d_in, const int* in_sizes, int n_in,
                              void* d_out, int out_size, void* d_ws, size_t ws_size,
                              hipStream_t stream) {
    const void*  in_spikes = d_in[0];
    const float* weights   = (const float*)d_in[1];
    const int*   targets   = (const int*)d_in[2];
    float*       out_f     = (float*)d_out;

    char* w = (char*)d_ws;
    int*   cnt       = (int*)w;                  // [0],[1] frontier counts
    float* decay_tab = (float*)(w + 256);        // 51 floats
    float* pot       = (float*)(w + 512);
    float* acc       = pot + N_TOTAL;
    int*   last_up   = (int*)(acc + N_TOTAL);
    int*   fr0       = last_up + N_TOTAL;
    int*   fr1       = fr0 + N_TOTAL;
    unsigned char* fired = (unsigned char*)(fr1 + N_TOTAL);
    size_t base_bytes = (size_t)((char*)(fired + N_TOTAL) - w);
    size_t rep_off    = (base_bytes + 255) & ~(size_t)255;
    float* rep        = (float*)(w + rep_off);
    size_t need       = rep_off + (size_t)N_CHUNK * 2 * HALF_SZ * 4;
    const bool dense_ok = ws_size >= need;

    hipMemsetAsync(cnt, 0, 16, stream);
    init_k<<<266, 256, 0, stream>>>((const unsigned int*)in_spikes,
                                    pot, acc, last_up, fired,
                                    fr0, cnt, out_f, decay_tab);

    int* fr[2] = {fr0, fr1};
    for (int t = 0; t < T_BIG; ++t) {
        const int cur = t & 1, nxt = cur ^ 1;
        const bool dstep = dense_ok && t >= DENSE_T_LO && t <= DENSE_T_HI;
        const int gate = dstep ? DENSE_THR : 0x7fffffff;
        scatter_k<<<512, 256, 0, stream>>>(fr[cur], &cnt[cur], &cnt[nxt],
                                           targets, weights, acc, gate);
        if (dstep) {
            dense_scatter_k<<<2 * N_CHUNK, 1024, 0, stream>>>(
                fr[cur], &cnt[cur], targets, weights, rep);
            dense_update_k<<<65, 1024, 0, stream>>>(
                rep, &cnt[cur], pot, last_up, fired,
                fr[nxt], &cnt[nxt], out_f, decay_tab, t);
        }
        update_k<<<258, 256, 0, stream>>>(pot, acc, last_up, fired,
                                          fr[nxt], &cnt[nxt], out_f,
                                          decay_tab, t, &cnt[cur], gate);
    }
    tail_k<<<1, 1024, 0, stream>>>(pot, acc, last_up, fired, fr0, fr1, cnt,
                                   targets, weights, out_f, decay_tab);
}